// Round 6
// baseline (804.326 us; speedup 1.0000x reference)
//
#include <hip/hip_runtime.h>
#include <cstddef>

#define S 512
#define SHIFT_HW 18      // 512*512 = 1<<18
#define NCOL 16384

// workspace layout (float offsets). q/k/v are COLUMN-MAJOR blocked:
//   qb[bh][n][r], bh in [0,16), n in [0,16384), r in [0,96)
// so K1's stores (r contiguous) and K3/K5's tile loads (n-range contiguous)
// are both coalesced. Row-major gave 2x WRITE_SIZE (partial line RMW).
#define QB_OFF 0ull
#define KB_OFF 25165824ull
#define VB_OFF 50331648ull
#define SQ_OFF 75644928ull
#define SK_OFF 75646464ull
#define A_OFF  75648000ull

#define QS_STRIDE 324    // 18x18 halo exactly; (4*dch+18*dy) mod 32 <=2-way

// ---------------------------------------------------------------------------
// K1 v9: fused 1x1 qkv conv + 3x3 depthwise (zero pad) + scatter to
// column-major blocked layout. grid (32,32,2), block 384. 16x16 tile.
// History: v4 LDS weights (VALUBusy 34->57); v6/v7 register tiling REGRESSED
// (occupancy loss; uniform ds_read broadcast is HW-deduped). v8 LDS diet
// 46080->40896 B + single qws staged during depthwise => occ 17.7->40.7%,
// 326us -- BUT launch_bounds(384,6)'s ~85-VGPR cap made the spiller cascade
// to VGPR=40: xv[48] spilled to scratch (WRITE +120MB = 2048x324x192B,
// FETCH +91MB). v9 keeps the v8 LDS/staging and sets (384,4) (cap 128):
// round-1 evidence shows this dataflow compiles to ~56 VGPR spill-free,
// and 56 VGPR still permits 6 waves/SIMD (6x56=336<=512) => 4 blocks/CU
// with xv resident.
// ---------------------------------------------------------------------------
__global__ __launch_bounds__(384, 4) void k1_qkv_dw(
    const float* __restrict__ x, const float* __restrict__ qkv_w,
    const float* __restrict__ dw_w,
    float* __restrict__ qb, float* __restrict__ kb, float* __restrict__ vb)
{
  const int t = threadIdx.x;
  const int b = blockIdx.z;
  const int W0 = blockIdx.x * 16, H0 = blockIdx.y * 16;
  __shared__ float qs[24 * QS_STRIDE];   // 24-ch group over 18x18 halo
  __shared__ float dws[1296];            // all depthwise weights (144 ch x 9)
  __shared__ float qws[1152];            // single-buffered 1x1 weights (24x48)

  for (int i = t; i < 1296; i += 384) dws[i] = dw_w[i];
  // prologue: stage group 0 weights
  for (int i = t; i < 288; i += 384)
    ((float4*)qws)[i] = ((const float4*)qkv_w)[i];

  // per-thread halo pixel, x channels held in registers across all 6 groups
  float xv[48];
  const int p  = t;
  const int hy = p / 18, hx = p % 18;            // valid for t<324
  const int Hg = H0 - 1 + hy, Wg = W0 - 1 + hx;
  const bool inb = (t < 324) && (Hg >= 0) && (Hg < S) && (Wg >= 0) && (Wg < S);
  const float* xb = x + ((size_t)b * 48 << SHIFT_HW) + (inb ? ((Hg << 9) + Wg) : 0);
  #pragma unroll
  for (int ic = 0; ic < 48; ++ic) {
    float v = 0.0f;
    if (inb) v = xb[(size_t)ic << SHIFT_HW];
    xv[ic] = v;
  }

  // depthwise task: thread owns (ch, output row y), all 16 x-positions
  const int ch = t >> 4;                 // 0..23 (channel within group)
  const int y  = t & 15;                 // output row within tile
  const int nb = (blockIdx.y * 4 + (y >> 2)) * 128 + blockIdx.x * 4;
  const float* qrow = qs + ch * QS_STRIDE + y * 18;  // halo rows y..y+2

  __syncthreads();   // dws + qws(g=0) ready

  #pragma unroll 1
  for (int g = 0; g < 6; ++g) {
    // ---- pointwise GEMM: 24 output channels for this group, halo pixels ----
    // weights from LDS, wave-uniform b128 reads (HW broadcast, conflict-free)
    if (t < 324) {
      const float* wgp = qws;
      #pragma unroll
      for (int oc = 0; oc < 24; oc += 2) {
        float a0 = 0.f, a1 = 0.f;
        #pragma unroll
        for (int ic4 = 0; ic4 < 12; ++ic4) {
          const float4 w0 = *(const float4*)(wgp + oc * 48 + ic4 * 4);
          const float4 w1 = *(const float4*)(wgp + (oc + 1) * 48 + ic4 * 4);
          a0 += w0.x * xv[ic4 * 4 + 0] + w0.y * xv[ic4 * 4 + 1]
              + w0.z * xv[ic4 * 4 + 2] + w0.w * xv[ic4 * 4 + 3];
          a1 += w1.x * xv[ic4 * 4 + 0] + w1.y * xv[ic4 * 4 + 1]
              + w1.z * xv[ic4 * 4 + 2] + w1.w * xv[ic4 * 4 + 3];
        }
        qs[oc * QS_STRIDE + p]       = a0;
        qs[(oc + 1) * QS_STRIDE + p] = a1;
      }
    }
    __syncthreads();

    // ---- stage next group's weights (qws idle during depthwise) ----------
    // load issued at phase start, ds_write at phase end: HBM latency hides
    // under the depthwise compute. Barriers order pw(g) reads -> overwrite.
    float4 stg;
    const bool do_stage = (g < 5) && (t < 288);
    if (do_stage) stg = *((const float4*)qkv_w + (g + 1) * 288 + t);

    // ---- depthwise 3x3 (sliding window) + coalesced float4 stores ----
    // out[xq] -> n = nb + (xq>>2), r = c*16 + (y&3)*4 + (xq&3):
    // one float4 per n, r contiguous. A wave's 16B pieces tile 128-256B
    // contiguous segments -> fully dirtied lines, no RMW.
    const int tensor = g >> 1;            // 0=q,1=k,2=v
    const int chbase = (g & 1) * 24;
    const int chg  = chbase + ch;         // channel within tensor
    const int head = chg / 6, c = chg - 6 * head;
    float* dst = (tensor == 0) ? qb : (tensor == 1) ? kb : vb;
    float* dstp = dst + (size_t)((b * 8 + head) * 16384 + nb) * 96
                      + c * 16 + (y & 3) * 4;
    const float* wp = dws + (tensor * 48 + chg) * 9;
    const float w0 = wp[0], w1 = wp[1], w2 = wp[2];
    const float w3 = wp[3], w4 = wp[4], w5 = wp[5];
    const float w6 = wp[6], w7 = wp[7], w8 = wp[8];

    float p00 = qrow[0], p01 = qrow[18], p02 = qrow[36];
    float p10 = qrow[1], p11 = qrow[19], p12 = qrow[37];
    #pragma unroll
    for (int wl = 0; wl < 4; ++wl) {
      float o[4];
      #pragma unroll
      for (int u = 0; u < 4; ++u) {
        const int xq = wl * 4 + u;
        const float n0 = qrow[xq + 2];
        const float n1 = qrow[xq + 20];
        const float n2 = qrow[xq + 38];
        o[u] = w0 * p00 + w1 * p10 + w2 * n0
             + w3 * p01 + w4 * p11 + w5 * n1
             + w6 * p02 + w7 * p12 + w8 * n2;
        p00 = p10; p01 = p11; p02 = p12;
        p10 = n0;  p11 = n1;  p12 = n2;
      }
      float4 v4 = {o[0], o[1], o[2], o[3]};
      *(float4*)(dstp + (size_t)wl * 96) = v4;
    }

    if (do_stage) ((float4*)qws)[t] = stg;
    __syncthreads();
  }
}

// ---------------------------------------------------------------------------
// K3 v6: Gram G[bh] = q@k^T (96x96, K=16384) + row sum-squares. Column-major
// input: tile load is a flat contiguous copy.
// v6 vs v5: (a) grid (32,16)->(64,16): the 32-chunk split was an atomic-
// contention fix; atomics are gone, and 512 blocks = 2 blocks/CU left global
// load latency exposed (serial load->barrier->compute per stage). 1024
// blocks restores residency. (b) register software pipeline: stage st+1's
// 12 float4 global loads are ISSUED before computing stage st, so ~900cy HBM
// latency hides under the 64x36-FMA compute phase. VGPR ~115 < cap 170.
// ---------------------------------------------------------------------------
__global__ __launch_bounds__(256, 3) void k3_gram(
    const float* __restrict__ qb, const float* __restrict__ kb,
    float* __restrict__ Gp, float* __restrict__ sq, float* __restrict__ sk)
{
  const int t  = threadIdx.x;
  const int bh = blockIdx.y;
  const int n0 = blockIdx.x * 256;
  __shared__ float qt[6144];   // [64 n][96 r] flat
  __shared__ float kt[6144];
  const int ti = t >> 4, tj = t & 15;
  float acc[6][6];
  #pragma unroll
  for (int r = 0; r < 6; ++r)
    #pragma unroll
    for (int s_ = 0; s_ < 6; ++s_) acc[r][s_] = 0.f;
  float ss = 0.f;
  const float* qbase = qb + (size_t)bh * 16384 * 96;
  const float* kbase = kb + (size_t)bh * 16384 * 96;

  // prologue: prefetch stage 0 into registers
  float4 pq[6], pk[6];
  {
    const float4* qsrc = (const float4*)(qbase + (size_t)n0 * 96);
    const float4* ksrc = (const float4*)(kbase + (size_t)n0 * 96);
    #pragma unroll
    for (int r = 0; r < 6; ++r) {
      pq[r] = qsrc[r * 256 + t];
      pk[r] = ksrc[r * 256 + t];
    }
  }

  #pragma unroll 1
  for (int st = 0; st < 4; ++st) {
    // write prefetched stage to LDS (prev iter's trailing barrier ordered
    // all reads of the old contents before this overwrite)
    #pragma unroll
    for (int r = 0; r < 6; ++r) {
      ((float4*)qt)[r * 256 + t] = pq[r];
      ((float4*)kt)[r * 256 + t] = pk[r];
    }
    __syncthreads();
    // issue next stage's global loads; latency hides under compute below
    if (st < 3) {
      const float4* qsrc = (const float4*)(qbase + (size_t)(n0 + (st + 1) * 64) * 96);
      const float4* ksrc = (const float4*)(kbase + (size_t)(n0 + (st + 1) * 64) * 96);
      #pragma unroll
      for (int r = 0; r < 6; ++r) {
        pq[r] = qsrc[r * 256 + t];
        pk[r] = ksrc[r * 256 + t];
      }
    }
    #pragma unroll 2
    for (int nn = 0; nn < 64; ++nn) {
      const float* qr = qt + nn * 96 + ti * 6;
      const float* kr = kt + nn * 96 + tj * 6;
      const float2 q0 = *(const float2*)(qr);
      const float2 q1 = *(const float2*)(qr + 2);
      const float2 q2 = *(const float2*)(qr + 4);
      const float2 k0 = *(const float2*)(kr);
      const float2 k1 = *(const float2*)(kr + 2);
      const float2 k2 = *(const float2*)(kr + 4);
      const float qv[6] = {q0.x, q0.y, q1.x, q1.y, q2.x, q2.y};
      const float kv[6] = {k0.x, k0.y, k1.x, k1.y, k2.x, k2.y};
      #pragma unroll
      for (int r = 0; r < 6; ++r)
        #pragma unroll
        for (int s_ = 0; s_ < 6; ++s_)
          acc[r][s_] += qv[r] * kv[s_];
    }
    if (t < 192) {                          // sum-squares for norms
      const float* base = (t < 96) ? qt : kt;
      const int srow = (t < 96) ? t : (t - 96);
      float s2 = 0.f;
      #pragma unroll 8
      for (int nn = 0; nn < 64; ++nn) {
        const float v = base[nn * 96 + srow];
        s2 += v * v;
      }
      ss += s2;
    }
    __syncthreads();   // all LDS reads done before next overwrite
  }
  // non-atomic partial store: Gp[p][bh][9216], p = blockIdx.x in [0,64)
  float* Gb = Gp + (size_t)(blockIdx.x * 16 + bh) * 9216;
  #pragma unroll
  for (int r = 0; r < 6; ++r)
    #pragma unroll
    for (int s_ = 0; s_ < 6; ++s_)
      Gb[(ti * 6 + r) * 96 + (tj * 6 + s_)] = acc[r][s_];
  if (t < 96)       atomicAdd(sq + bh * 96 + t,        ss);
  else if (t < 192) atomicAdd(sk + bh * 96 + (t - 96), ss);
}

// ---------------------------------------------------------------------------
// K4 v3: sum 64 Gram partials + normalize logits + temperature + row softmax.
// grid (96 rows, 16 bh), block 128. Partial sum: 64 coalesced 384B loads
// per block (37.7 MB total, L2/L3-resident).
// ---------------------------------------------------------------------------
__global__ __launch_bounds__(128) void k4_softmax(
    const float* __restrict__ Gp, const float* __restrict__ sq,
    const float* __restrict__ sk, const float* __restrict__ temp,
    float* __restrict__ A)
{
  const int i  = blockIdx.x;
  const int bh = blockIdx.y;
  const int h  = bh & 7;
  const int t  = threadIdx.x;
  __shared__ float red[128];

  const float nq    = fmaxf(sqrtf(sq[bh * 96 + i]), 1e-12f);
  const float scale = temp[h] / nq;
  float logit = 0.f, val = -1e30f;
  if (t < 96) {
    float gsum = 0.f;
    #pragma unroll 8
    for (int p = 0; p < 64; ++p)
      gsum += Gp[(size_t)(p * 16 + bh) * 9216 + i * 96 + t];
    const float nk = fmaxf(sqrtf(sk[bh * 96 + t]), 1e-12f);
    logit = gsum * scale / nk;
    val = logit;
  }
  red[t] = val; __syncthreads();
  #pragma unroll
  for (int o = 64; o > 0; o >>= 1) {
    if (t < o) red[t] = fmaxf(red[t], red[t + o]);
    __syncthreads();
  }
  const float m = red[0]; __syncthreads();
  const float e = (t < 96) ? __expf(logit - m) : 0.f;
  red[t] = e; __syncthreads();
  #pragma unroll
  for (int o = 64; o > 0; o >>= 1) {
    if (t < o) red[t] += red[t + o];
    __syncthreads();
  }
  const float ssum = red[0];
  if (t < 96) A[(size_t)bh * 9216 + i * 96 + t] = e / ssum;
}

// ---------------------------------------------------------------------------
// K5 v4: out = proj( from_blocks( A @ v ) ). One block = 16 attention cols.
// 384 threads: thread=(h(8) x ip(48)) reads its 2 A-rows ONCE (A traffic
// 0.60 GB); XCD swizzle pins batch per XCD-half (per-XCD A set 2.36 MB < L2).
// ---------------------------------------------------------------------------
__global__ __launch_bounds__(384, 4) void k5_av_proj(
    const float* __restrict__ vb, const float* __restrict__ A,
    const float* __restrict__ pw, float* __restrict__ out)
{
  const int t  = threadIdx.x;
  // XCD-aware decode: consecutive blockIdx round-robin XCDs (mod 8).
  // XCDs 0-3 -> b=0, XCDs 4-7 -> b=1; within-b index covers 1024 tiles.
  const int flat = blockIdx.x;
  const int xcd  = flat & 7;
  const int b    = xcd >> 2;
  const int idx  = (xcd & 3) * 256 + (flat >> 3);   // [0,1024)
  const int wg   = idx & 7, hh = idx >> 3;
  const int n0 = hh * 128 + wg * 16;
  __shared__ float smem[12288];   // phase 0-1: vt[h][r][16 nl]; phase 2-3: ao

  // phase 0: load v tile. global: 16 segments of 64B per wave; LDS scatter
  // (16u+nl banks) is 4-way on a handful of insts (negligible).
  #pragma unroll
  for (int it = 0; it < 8; ++it) {
    const int i4  = it * 384 + t;          // [0, 3072)
    const int h   = i4 / 384;
    const int q   = i4 - h * 384;
    const int r4g = q >> 6;
    const int rem = q & 63;
    const int nl  = rem >> 2;
    const int r4  = r4g * 4 + (rem & 3);
    const float4 v = *(const float4*)(vb
        + (size_t)((b * 8 + h) * 16384 + n0 + nl) * 96 + r4 * 4);
    float* dl = smem + (h * 96 + r4 * 4) * 16 + nl;
    dl[0] = v.x; dl[16] = v.y; dl[32] = v.z; dl[48] = v.w;
  }
  __syncthreads();

  // phase 1: A @ v. thread owns (h, ip): output rows i0=2ip, i0+1, all 4 n4.
  const int h  = t / 48;
  const int ip = t - h * 48;
  const int i0 = ip * 2;
  const float* arow0 = A + (size_t)((b * 8 + h) * 96 + i0) * 96;
  const float* arow1 = arow0 + 96;
  const float* vbase = smem + h * 1536;
  float4 r0[4], r1[4];
  #pragma unroll
  for (int n4 = 0; n4 < 4; ++n4) {
    r0[n4] = float4{0, 0, 0, 0};
    r1[n4] = float4{0, 0, 0, 0};
  }
  #pragma unroll 2
  for (int j4 = 0; j4 < 24; ++j4) {
    const float4 w0 = *(const float4*)(arow0 + j4 * 4);
    const float4 w1 = *(const float4*)(arow1 + j4 * 4);
    const float w0a[4] = {w0.x, w0.y, w0.z, w0.w};
    const float w1a[4] = {w1.x, w1.y, w1.z, w1.w};
    #pragma unroll
    for (int u = 0; u < 4; ++u) {
      const float* vp = vbase + (j4 * 4 + u) * 16;
      const float wu0 = w0a[u], wu1 = w1a[u];
      #pragma unroll
      for (int n4 = 0; n4 < 4; ++n4) {
        const float4 vv = *(const float4*)(vp + n4 * 4);
        r0[n4].x += wu0 * vv.x; r0[n4].y += wu0 * vv.y;
        r0[n4].z += wu0 * vv.z; r0[n4].w += wu0 * vv.w;
        r1[n4].x += wu1 * vv.x; r1[n4].y += wu1 * vv.y;
        r1[n4].z += wu1 * vv.z; r1[n4].w += wu1 * vv.w;
      }
    }
  }
  __syncthreads();   // all vt reads done; smem becomes ao

  // phase 2: write res into ao. logical layout ao[ic][p][ww] with the ww-quad
  // rotated by (p>>1): slot q_phys = (q + (p>>1)) & 3 (spreads write banks;
  // phase 3 un-rotates).
  {
    const int ic0 = h * 6 + (i0 >> 4);
    const int p0w = i0 & 15;
    const int i1 = i0 + 1;
    const int ic1 = h * 6 + (i1 >> 4);
    const int p1w = i1 & 15;
    #pragma unroll
    for (int n4 = 0; n4 < 4; ++n4) {
      const int q0 = (n4 + (p0w >> 1)) & 3;
      const int q1 = (n4 + (p1w >> 1)) & 3;
      *(float4*)(smem + ic0 * 256 + p0w * 16 + q0 * 4) = r0[n4];
      *(float4*)(smem + ic1 * 256 + p1w * 16 + q1 * 4) = r1[n4];
    }
  }
  __syncthreads();

  // phase 3: proj 1x1: thread owns one output pixel across 48 channels
  if (t < 256) {
    const int xl = t & 63, ph = t >> 6;
    const int p  = ph * 4 + (xl & 3);
    const int wwl = xl >> 2;
    const int qp = ((wwl >> 2) + (p >> 1)) & 3;       // un-rotate
    const int wwp = qp * 4 + (wwl & 3);
    float sv[48];
    #pragma unroll
    for (int ic = 0; ic < 48; ++ic) sv[ic] = smem[ic * 256 + p * 16 + wwp];
    const int H = hh * 4 + ph;
    const int Wp = wg * 64 + xl;
    float* outp = out + ((size_t)b * 48 << SHIFT_HW) + (H << 9) + Wp;
    #pragma unroll 1
    for (int oc = 0; oc < 48; oc += 2) {
      float acc0 = 0.f, acc1 = 0.f;
      #pragma unroll
      for (int ic = 0; ic < 48; ++ic) {
        acc0 += pw[oc * 48 + ic]       * sv[ic];   // uniform -> s_loads
        acc1 += pw[(oc + 1) * 48 + ic] * sv[ic];
      }
      outp[(size_t)oc << SHIFT_HW]       = acc0;
      outp[(size_t)(oc + 1) << SHIFT_HW] = acc1;
    }
  }
}

// ---------------------------------------------------------------------------
extern "C" void kernel_launch(void* const* d_in, const int* in_sizes, int n_in,
                              void* d_out, int out_size, void* d_ws, size_t ws_size,
                              hipStream_t stream) {
  const float* x      = (const float*)d_in[0];
  const float* qkv_w  = (const float*)d_in[1];
  const float* dw_w   = (const float*)d_in[2];
  const float* proj_w = (const float*)d_in[3];
  const float* temp   = (const float*)d_in[4];
  float* ws = (float*)d_ws;
  float* qb = ws + QB_OFF;
  float* kb = ws + KB_OFF;
  float* vb = ws + VB_OFF;
  float* sq = ws + SQ_OFF;
  float* sk = ws + SK_OFF;
  float* A  = ws + A_OFF;
  // partial-G scratch lives in d_out (37.7 MB needed, ~100 MB available);
  // K5 fully overwrites d_out afterwards.
  float* Gp = (float*)d_out;

  // zero sq + sk only (G atomics are gone)
  hipMemsetAsync(sq, 0, (size_t)3072 * sizeof(float), stream);

  k1_qkv_dw<<<dim3(32, 32, 2), 384, 0, stream>>>(x, qkv_w, dw_w, qb, kb, vb);
  k3_gram<<<dim3(64, 16), 256, 0, stream>>>(qb, kb, Gp, sq, sk);
  k4_softmax<<<dim3(96, 16), 128, 0, stream>>>(Gp, sq, sk, temp, A);
  k5_av_proj<<<2048, 384, 0, stream>>>(vb, A, proj_w, (float*)d_out);
}